// Round 3
// baseline (425.119 us; speedup 1.0000x reference)
//
#include <hip/hip_runtime.h>
#include <stdint.h>

// B=8, C=128, N=4096 (64x64), GROUPS=8 (16 ch/group)

typedef __attribute__((ext_vector_type(8))) short short8;
typedef __attribute__((ext_vector_type(4))) float f32x4;

#define MFMA_BF16(a, b, c) __builtin_amdgcn_mfma_f32_16x16x32_bf16((a), (b), (c), 0, 0, 0)
#define EXP2(x) __builtin_amdgcn_exp2f(x)

// (1/sqrt(128)) * log2(e) — folded into Q at k_qkv store time
#define QSCALE 0.12751743f

__device__ __forceinline__ unsigned short f2bf(float f) {
    unsigned int u = __builtin_bit_cast(unsigned int, f);
    u += 0x7FFFu + ((u >> 16) & 1u);   // RNE (finite values only)
    return (unsigned short)(u >> 16);
}

__device__ __forceinline__ short8 ldg8(const unsigned short* p) {
    return __builtin_bit_cast(short8, *(const uint4*)p);
}

// max over the 16-lane DPP row (j = lane&15 dimension), VALU pipe not LDS pipe
__device__ __forceinline__ float rowmax16(float v) {
    int x, y;
    x = __builtin_bit_cast(int, v);
    y = __builtin_amdgcn_update_dpp(x, x, 0x121, 0xF, 0xF, false);  // row_ror:1
    v = fmaxf(v, __builtin_bit_cast(float, y));
    x = __builtin_bit_cast(int, v);
    y = __builtin_amdgcn_update_dpp(x, x, 0x122, 0xF, 0xF, false);  // row_ror:2
    v = fmaxf(v, __builtin_bit_cast(float, y));
    x = __builtin_bit_cast(int, v);
    y = __builtin_amdgcn_update_dpp(x, x, 0x124, 0xF, 0xF, false);  // row_ror:4
    v = fmaxf(v, __builtin_bit_cast(float, y));
    x = __builtin_bit_cast(int, v);
    y = __builtin_amdgcn_update_dpp(x, x, 0x128, 0xF, 0xF, false);  // row_ror:8
    v = fmaxf(v, __builtin_bit_cast(float, y));
    return v;
}

// ---------------- Kernel 1: GroupNorm stats (mean, rstd) per (b,g) ----------------
__global__ __launch_bounds__(256) void k_stats(const float* __restrict__ x,
                                               float* __restrict__ stats) {
    int grp = blockIdx.x;                       // 0..63  (b*8+g); group slab is contiguous
    const float* p = x + (size_t)grp * 65536;
    float s = 0.f, sq = 0.f;
    for (int i = threadIdx.x * 4; i < 65536; i += 1024) {
        float4 v = *(const float4*)(p + i);
        s  += v.x + v.y + v.z + v.w;
        sq += v.x*v.x + v.y*v.y + v.z*v.z + v.w*v.w;
    }
#pragma unroll
    for (int m = 1; m < 64; m <<= 1) { s += __shfl_xor(s, m, 64); sq += __shfl_xor(sq, m, 64); }
    __shared__ float ss[4], ssq[4];
    int w = threadIdx.x >> 6;
    if ((threadIdx.x & 63) == 0) { ss[w] = s; ssq[w] = sq; }
    __syncthreads();
    if (threadIdx.x == 0) {
        float ts = ss[0] + ss[1] + ss[2] + ss[3];
        float tq = ssq[0] + ssq[1] + ssq[2] + ssq[3];
        float mean = ts * (1.f / 65536.f);
        float var  = tq * (1.f / 65536.f) - mean * mean;
        stats[grp * 2]     = mean;
        stats[grp * 2 + 1] = rsqrtf(var + 1e-5f);
    }
}

// ---------------- Kernel 2: fused GroupNorm-apply + QKV GEMM ----------------
// Q (pre-scaled by QSCALE), K as bf16 [b][n][c]; V as bf16 [b][c][n] (packed stores).
__global__ __launch_bounds__(256) void k_qkv(const float* __restrict__ x,
                                             const float* __restrict__ stats,
                                             const float* __restrict__ gn_w,
                                             const float* __restrict__ gn_b,
                                             const float* __restrict__ qkv_w,
                                             const float* __restrict__ qkv_b,
                                             unsigned short* __restrict__ q_ws,
                                             unsigned short* __restrict__ k_ws,
                                             unsigned short* __restrict__ v_ws) {
    __shared__ unsigned short h_lds[64][136];   // [n][c], +8 pad
    __shared__ unsigned short v_stage[128][72]; // [c][n_local], +8 pad (16B-aligned rows)
    const int tid  = threadIdx.x;
    const int b    = blockIdx.x >> 6;
    const int n0   = (blockIdx.x & 63) << 6;
    const int lane = tid & 63, wave = tid >> 6;
    const int l15  = lane & 15, q4 = lane >> 4;

    // normalize x tile -> bf16 -> h_lds[n][c]
    {
        int cb = tid >> 4;            // 0..15
        int nn = (tid & 15) << 2;     // 0..60
#pragma unroll
        for (int k = 0; k < 8; ++k) {
            int c = cb + (k << 4);
            float4 v = *(const float4*)(x + ((size_t)(b * 128 + c) << 12) + n0 + nn);
            int g = c >> 4;
            float mean = stats[(b * 8 + g) * 2];
            float rstd = stats[(b * 8 + g) * 2 + 1];
            float ga = gn_w[c] * rstd;
            float be = gn_b[c] - mean * ga;
            h_lds[nn + 0][c] = f2bf(v.x * ga + be);
            h_lds[nn + 1][c] = f2bf(v.y * ga + be);
            h_lds[nn + 2][c] = f2bf(v.z * ga + be);
            h_lds[nn + 3][c] = f2bf(v.w * ga + be);
        }
    }
    __syncthreads();

    short8 bfrag[4][4];               // [nt][ks]  B[k=c][n], n=l15
#pragma unroll
    for (int nt = 0; nt < 4; ++nt)
#pragma unroll
        for (int ks = 0; ks < 4; ++ks)
            bfrag[nt][ks] = *(const short8*)&h_lds[nt * 16 + l15][ks * 32 + q4 * 8];

#pragma unroll
    for (int ot = 0; ot < 6; ++ot) {
        int o0 = wave * 96 + ot * 16;                 // 16-row tile is purely Q, K, or V
        short8 af[4];                                 // A[m=o][k=c], m=l15
        const float* wp = qkv_w + (size_t)(o0 + l15) * 128 + q4 * 8;
#pragma unroll
        for (int ks = 0; ks < 4; ++ks) {
            float4 w0 = *(const float4*)(wp + ks * 32);
            float4 w1 = *(const float4*)(wp + ks * 32 + 4);
            short8 t;
            t[0] = (short)f2bf(w0.x); t[1] = (short)f2bf(w0.y);
            t[2] = (short)f2bf(w0.z); t[3] = (short)f2bf(w0.w);
            t[4] = (short)f2bf(w1.x); t[5] = (short)f2bf(w1.y);
            t[6] = (short)f2bf(w1.z); t[7] = (short)f2bf(w1.w);
            af[ks] = t;
        }
        float bias[4];
#pragma unroll
        for (int r = 0; r < 4; ++r) bias[r] = qkv_b[o0 + q4 * 4 + r];
        float qs = (o0 < 128) ? QSCALE : 1.0f;

#pragma unroll
        for (int nt = 0; nt < 4; ++nt) {
            f32x4 acc = {0.f, 0.f, 0.f, 0.f};
#pragma unroll
            for (int ks = 0; ks < 4; ++ks)
                acc = MFMA_BF16(af[ks], bfrag[nt][ks], acc);
            // D[row = o0+q4*4+r][col = n0+nt*16+l15]
            int n = n0 + nt * 16 + l15;
            if (o0 < 256) {           // Q or K: [n][c] layout, 4 consecutive c -> 8B store
                unsigned short* dst = (o0 < 128) ? q_ws : k_ws;
                int oo = (o0 < 128) ? o0 : (o0 - 128);
                unsigned int lo = (unsigned int)f2bf((acc[0] + bias[0]) * qs) |
                                  ((unsigned int)f2bf((acc[1] + bias[1]) * qs) << 16);
                unsigned int hi = (unsigned int)f2bf((acc[2] + bias[2]) * qs) |
                                  ((unsigned int)f2bf((acc[3] + bias[3]) * qs) << 16);
                uint2 pk; pk.x = lo; pk.y = hi;
                *(uint2*)&dst[((size_t)(b * 4096 + n) << 7) + oo + q4 * 4] = pk;
            } else {                  // V: stage to LDS [c][n_local]
#pragma unroll
                for (int r = 0; r < 4; ++r) {
                    int c = o0 - 256 + q4 * 4 + r;
                    v_stage[c][nt * 16 + l15] = f2bf(acc[r] + bias[r]);
                }
            }
        }
    }
    __syncthreads();
    // packed V store: thread t copies half-row (32 shorts) of v_stage row c=t>>1
    {
        int c = tid >> 1, h = tid & 1;
        uint4* gdst = (uint4*)(v_ws + ((size_t)(b * 128 + c) << 12) + n0 + h * 32);
        const unsigned short* lsrc = &v_stage[c][h * 32];
#pragma unroll
        for (int k = 0; k < 4; ++k) gdst[k] = *(const uint4*)(lsrc + k * 8);
    }
}

// ---------------- Kernel 3: flash attention + fused proj + residual ----------------
// block = (b, 64-row i-tile); wave w owns rows i0+16w..+15.
// K tile staged in LDS (shared by 4 waves); V fragments streamed from global;
// row state (m,l,alpha) lives in (quad,reg) space: no cross-lane softmax traffic.
__global__ __launch_bounds__(256, 2) void k_attn(const unsigned short* __restrict__ q_ws,
                                                 const unsigned short* __restrict__ k_ws,
                                                 const unsigned short* __restrict__ v_ws,
                                                 const float* __restrict__ x,
                                                 const float* __restrict__ proj_w,
                                                 const float* __restrict__ proj_b,
                                                 float* __restrict__ out) {
    __shared__ unsigned short K_lds[64][136];    // [j][c] during loop; [n][c] O-stage after
    __shared__ unsigned short P_lds[4][16][72];  // per wave [i][j], 144B rows (16B-aligned)

    const int tid  = threadIdx.x;
    const int b    = blockIdx.x >> 6;
    const int i0   = (blockIdx.x & 63) << 6;
    const int lane = tid & 63, wave = tid >> 6;
    const int l15  = lane & 15, q4 = lane >> 4;

    const short8 ones = {(short)0x3F80, (short)0x3F80, (short)0x3F80, (short)0x3F80,
                         (short)0x3F80, (short)0x3F80, (short)0x3F80, (short)0x3F80};

    short8 qf[4];                                // A[m=i][k=c], m=l15  (pre-scaled by QSCALE)
    {
        const unsigned short* qp =
            q_ws + ((size_t)(b * 4096 + i0 + wave * 16 + l15) << 7) + q4 * 8;
#pragma unroll
        for (int ks = 0; ks < 4; ++ks) qf[ks] = ldg8(qp + ks * 32);
    }

    float mrow[4];
    f32x4 lrow = {0.f, 0.f, 0.f, 0.f};
#pragma unroll
    for (int r = 0; r < 4; ++r) mrow[r] = -1e30f;
    f32x4 acc_o[8];                              // O[i=q4*4+r][c = ct*16 + l15]
#pragma unroll
    for (int ct = 0; ct < 8; ++ct) acc_o[ct] = (f32x4){0.f, 0.f, 0.f, 0.f};

    const unsigned short* kbase = k_ws + ((size_t)b << 19);
    const unsigned short* vbase = v_ws + ((size_t)b << 19);

    for (int it = 0; it < 64; ++it) {
        int j0 = it << 6;
        __syncthreads();                          // prior iter's K_lds reads done
        {   // stage K tile [64 j][128 c]: thread t -> row t>>2, quarter t&3
            int r = tid >> 2, q = tid & 3;
            const uint4* src = (const uint4*)(kbase + ((size_t)(j0 + r) << 7) + q * 32);
#pragma unroll
            for (int k = 0; k < 4; ++k)
                *(uint4*)&K_lds[r][q * 32 + k * 8] = src[k];
        }
        __syncthreads();

        // V fragments direct from global (B[k=j][n=c]); issue early, used after softmax
        short8 vf[2][8];
#pragma unroll
        for (int ks = 0; ks < 2; ++ks)
#pragma unroll
            for (int ct = 0; ct < 8; ++ct)
                vf[ks][ct] = ldg8(vbase + ((size_t)(ct * 16 + l15) << 12) +
                                  j0 + ks * 32 + q4 * 8);

        // S = Q K^T (Q pre-scaled): D row = i (q4*4+r), col = j (l15)
        f32x4 s[4];
#pragma unroll
        for (int jt = 0; jt < 4; ++jt) {
            f32x4 a = {0.f, 0.f, 0.f, 0.f};
#pragma unroll
            for (int ks = 0; ks < 4; ++ks) {
                short8 kf = *(const short8*)&K_lds[jt * 16 + l15][ks * 32 + q4 * 8];
                a = MFMA_BF16(qf[ks], kf, a);
            }
            s[jt] = a;
        }

        // online softmax in base-2; row state in (quad,reg) space, max via DPP (VALU)
        float al[4];
#pragma unroll
        for (int r = 0; r < 4; ++r) {
            float rm = fmaxf(fmaxf(s[0][r], s[1][r]), fmaxf(s[2][r], s[3][r]));
            rm = rowmax16(rm);
            float mn = fmaxf(mrow[r], rm);
            al[r] = EXP2(mrow[r] - mn);
            mrow[r] = mn;
        }
#pragma unroll
        for (int jt = 0; jt < 4; ++jt)
#pragma unroll
            for (int r = 0; r < 4; ++r)
                P_lds[wave][q4 * 4 + r][jt * 16 + l15] = f2bf(EXP2(s[jt][r] - mrow[r]));

        // P fragments (A[m=i][k=j]); reused for the l-MFMA and PV
        short8 pf0 = *(const short8*)&P_lds[wave][l15][q4 * 8];
        short8 pf1 = *(const short8*)&P_lds[wave][l15][32 + q4 * 8];

        // l = l*alpha + P.1  (ones-MFMA: every col of D holds the row sum)
        f32x4 lv;
#pragma unroll
        for (int r = 0; r < 4; ++r) lv[r] = lrow[r] * al[r];
        lv = MFMA_BF16(pf1, ones, MFMA_BF16(pf0, ones, lv));
        lrow = lv;

        // rescale O rows by alpha (register-local), then O += P V^T
#pragma unroll
        for (int ct = 0; ct < 8; ++ct)
#pragma unroll
            for (int r = 0; r < 4; ++r) acc_o[ct][r] *= al[r];
#pragma unroll
        for (int ct = 0; ct < 8; ++ct) acc_o[ct] = MFMA_BF16(pf0, vf[0][ct], acc_o[ct]);
#pragma unroll
        for (int ct = 0; ct < 8; ++ct) acc_o[ct] = MFMA_BF16(pf1, vf[1][ct], acc_o[ct]);
    }

    // normalize rows (register-local) and stage O into LDS as [n_local][c]
    __syncthreads();                              // done with K_lds as K
    {
        float rl[4];
#pragma unroll
        for (int r = 0; r < 4; ++r) rl[r] = 1.0f / lrow[r];
#pragma unroll
        for (int ct = 0; ct < 8; ++ct)
#pragma unroll
            for (int r = 0; r < 4; ++r)
                K_lds[wave * 16 + q4 * 4 + r][ct * 16 + l15] = f2bf(acc_o[ct][r] * rl[r]);
    }
    __syncthreads();

    // proj GEMM: out[o][n] = sum_c proj_w[o][c] * O[n][c]  + proj_b + x
    short8 bfrag[4][4];
#pragma unroll
    for (int nt = 0; nt < 4; ++nt)
#pragma unroll
        for (int ks = 0; ks < 4; ++ks)
            bfrag[nt][ks] = *(const short8*)&K_lds[nt * 16 + l15][ks * 32 + q4 * 8];

#pragma unroll
    for (int ot = 0; ot < 2; ++ot) {
        int o0 = wave * 32 + ot * 16;
        short8 af[4];
        const float* wp = proj_w + (size_t)(o0 + l15) * 128 + q4 * 8;
#pragma unroll
        for (int ks = 0; ks < 4; ++ks) {
            float4 w0 = *(const float4*)(wp + ks * 32);
            float4 w1 = *(const float4*)(wp + ks * 32 + 4);
            short8 t;
            t[0] = (short)f2bf(w0.x); t[1] = (short)f2bf(w0.y);
            t[2] = (short)f2bf(w0.z); t[3] = (short)f2bf(w0.w);
            t[4] = (short)f2bf(w1.x); t[5] = (short)f2bf(w1.y);
            t[6] = (short)f2bf(w1.z); t[7] = (short)f2bf(w1.w);
            af[ks] = t;
        }
        float pb[4];
#pragma unroll
        for (int r = 0; r < 4; ++r) pb[r] = proj_b[o0 + q4 * 4 + r];

#pragma unroll
        for (int nt = 0; nt < 4; ++nt) {
            f32x4 acc = {0.f, 0.f, 0.f, 0.f};
#pragma unroll
            for (int ks = 0; ks < 4; ++ks)
                acc = MFMA_BF16(af[ks], bfrag[nt][ks], acc);
#pragma unroll
            for (int r = 0; r < 4; ++r) {
                size_t idx = ((size_t)(b * 128 + o0 + q4 * 4 + r) << 12) + i0 + nt * 16 + l15;
                out[idx] = x[idx] + acc[r] + pb[r];
            }
        }
    }
}

// ---------------- launch ----------------
extern "C" void kernel_launch(void* const* d_in, const int* in_sizes, int n_in,
                              void* d_out, int out_size, void* d_ws, size_t ws_size,
                              hipStream_t stream) {
    const float* x      = (const float*)d_in[0];
    const float* gn_w   = (const float*)d_in[1];
    const float* gn_b   = (const float*)d_in[2];
    const float* qkv_w  = (const float*)d_in[3];
    const float* qkv_b  = (const float*)d_in[4];
    const float* proj_w = (const float*)d_in[5];
    const float* proj_b = (const float*)d_in[6];
    float* out = (float*)d_out;

    char* ws = (char*)d_ws;
    float* stats = (float*)ws;                                   // 64*2 floats
    unsigned short* q_ws = (unsigned short*)(ws + 1024);         // 8 MB each
    unsigned short* k_ws = q_ws + (size_t)8 * 4096 * 128;
    unsigned short* v_ws = k_ws + (size_t)8 * 4096 * 128;

    k_stats<<<64, 256, 0, stream>>>(x, stats);
    k_qkv<<<512, 256, 0, stream>>>(x, stats, gn_w, gn_b, qkv_w, qkv_b, q_ws, k_ws, v_ws);
    k_attn<<<512, 256, 0, stream>>>(q_ws, k_ws, v_ws, x, proj_w, proj_b, out);
}

// Round 4
// 248.984 us; speedup vs baseline: 1.7074x; 1.7074x over previous
//
#include <hip/hip_runtime.h>
#include <stdint.h>

// B=8, C=128, N=4096 (64x64), GROUPS=8 (16 ch/group)
// Flash split-KV: 4 chunks x 1024 j per (b, 64-row i-tile) -> grid 2048, ~5 blocks/CU.

typedef __attribute__((ext_vector_type(8))) short short8;
typedef __attribute__((ext_vector_type(4))) float f32x4;

#define MFMA_BF16(a, b, c) __builtin_amdgcn_mfma_f32_16x16x32_bf16((a), (b), (c), 0, 0, 0)
#define EXP2(x) __builtin_amdgcn_exp2f(x)

// (1/sqrt(128)) * log2(e) — folded into Q at k_qkv store time (softmax runs in base 2)
#define QSCALE 0.12751743f

__device__ __forceinline__ unsigned short f2bf(float f) {
    unsigned int u = __builtin_bit_cast(unsigned int, f);
    u += 0x7FFFu + ((u >> 16) & 1u);   // RNE (finite values only)
    return (unsigned short)(u >> 16);
}
__device__ __forceinline__ float bf2f(unsigned int lo16) {
    return __builtin_bit_cast(float, lo16 << 16);
}
__device__ __forceinline__ short8 ldg8(const unsigned short* p) {
    return __builtin_bit_cast(short8, *(const uint4*)p);
}

// max over the 16-lane DPP row (j = lane&15 dimension) — VALU pipe, not LDS pipe
__device__ __forceinline__ float rowmax16(float v) {
    int x, y;
    x = __builtin_bit_cast(int, v);
    y = __builtin_amdgcn_update_dpp(x, x, 0x121, 0xF, 0xF, false);  // row_ror:1
    v = fmaxf(v, __builtin_bit_cast(float, y));
    x = __builtin_bit_cast(int, v);
    y = __builtin_amdgcn_update_dpp(x, x, 0x122, 0xF, 0xF, false);  // row_ror:2
    v = fmaxf(v, __builtin_bit_cast(float, y));
    x = __builtin_bit_cast(int, v);
    y = __builtin_amdgcn_update_dpp(x, x, 0x124, 0xF, 0xF, false);  // row_ror:4
    v = fmaxf(v, __builtin_bit_cast(float, y));
    x = __builtin_bit_cast(int, v);
    y = __builtin_amdgcn_update_dpp(x, x, 0x128, 0xF, 0xF, false);  // row_ror:8
    v = fmaxf(v, __builtin_bit_cast(float, y));
    return v;
}

// ---------------- Kernel 1: GroupNorm stats (mean, rstd) per (b,g) ----------------
__global__ __launch_bounds__(256) void k_stats(const float* __restrict__ x,
                                               float* __restrict__ stats) {
    int grp = blockIdx.x;                       // 0..63  (b*8+g); group slab contiguous
    const float* p = x + (size_t)grp * 65536;
    float s = 0.f, sq = 0.f;
    for (int i = threadIdx.x * 4; i < 65536; i += 1024) {
        float4 v = *(const float4*)(p + i);
        s  += v.x + v.y + v.z + v.w;
        sq += v.x*v.x + v.y*v.y + v.z*v.z + v.w*v.w;
    }
#pragma unroll
    for (int m = 1; m < 64; m <<= 1) { s += __shfl_xor(s, m, 64); sq += __shfl_xor(sq, m, 64); }
    __shared__ float ss[4], ssq[4];
    int w = threadIdx.x >> 6;
    if ((threadIdx.x & 63) == 0) { ss[w] = s; ssq[w] = sq; }
    __syncthreads();
    if (threadIdx.x == 0) {
        float ts = ss[0] + ss[1] + ss[2] + ss[3];
        float tq = ssq[0] + ssq[1] + ssq[2] + ssq[3];
        float mean = ts * (1.f / 65536.f);
        float var  = tq * (1.f / 65536.f) - mean * mean;
        stats[grp * 2]     = mean;
        stats[grp * 2 + 1] = rsqrtf(var + 1e-5f);
    }
}

// ---------------- Kernel 1b: convert qkv_w / proj_w to bf16 once per call ----------
__global__ __launch_bounds__(256) void k_wconv(const float* __restrict__ qkv_w,
                                               const float* __restrict__ proj_w,
                                               unsigned short* __restrict__ wq,
                                               unsigned short* __restrict__ wp) {
    int i = (blockIdx.x * 256 + threadIdx.x) * 4;     // grid 64 -> 65536 elems
    const float* src; unsigned short* dst; int off;
    if (i < 49152) { src = qkv_w; dst = wq; off = i; }
    else           { src = proj_w; dst = wp; off = i - 49152; }
    float4 v = *(const float4*)(src + off);
    uint2 pk;
    pk.x = (unsigned int)f2bf(v.x) | ((unsigned int)f2bf(v.y) << 16);
    pk.y = (unsigned int)f2bf(v.z) | ((unsigned int)f2bf(v.w) << 16);
    *(uint2*)(dst + off) = pk;
}

// ---------------- Kernel 2: fused GroupNorm-apply + QKV GEMM ----------------
// Q (pre-scaled by QSCALE), K as bf16 [b][n][c]; V as bf16 [b][c][n].
__global__ __launch_bounds__(256) void k_qkv(const float* __restrict__ x,
                                             const float* __restrict__ stats,
                                             const float* __restrict__ gn_w,
                                             const float* __restrict__ gn_b,
                                             const unsigned short* __restrict__ wq,
                                             const float* __restrict__ qkv_b,
                                             unsigned short* __restrict__ q_ws,
                                             unsigned short* __restrict__ k_ws,
                                             unsigned short* __restrict__ v_ws) {
    __shared__ unsigned short h_lds[64][136];   // [n][c], +8 pad
    __shared__ unsigned short v_stage[128][72]; // [c][n_local], +8 pad
    const int tid  = threadIdx.x;
    const int b    = blockIdx.x >> 6;
    const int n0   = (blockIdx.x & 63) << 6;
    const int lane = tid & 63, wave = tid >> 6;
    const int l15  = lane & 15, q4 = lane >> 4;

    // normalize x tile -> bf16 -> h_lds[n][c]
    {
        int cb = tid >> 4;            // 0..15
        int nn = (tid & 15) << 2;     // 0..60
#pragma unroll
        for (int k = 0; k < 8; ++k) {
            int c = cb + (k << 4);
            float4 v = *(const float4*)(x + ((size_t)(b * 128 + c) << 12) + n0 + nn);
            int g = c >> 4;
            float mean = stats[(b * 8 + g) * 2];
            float rstd = stats[(b * 8 + g) * 2 + 1];
            float ga = gn_w[c] * rstd;
            float be = gn_b[c] - mean * ga;
            h_lds[nn + 0][c] = f2bf(v.x * ga + be);
            h_lds[nn + 1][c] = f2bf(v.y * ga + be);
            h_lds[nn + 2][c] = f2bf(v.z * ga + be);
            h_lds[nn + 3][c] = f2bf(v.w * ga + be);
        }
    }
    __syncthreads();

    short8 bfrag[4][4];               // B[k=c][n], n=l15
#pragma unroll
    for (int nt = 0; nt < 4; ++nt)
#pragma unroll
        for (int ks = 0; ks < 4; ++ks)
            bfrag[nt][ks] = *(const short8*)&h_lds[nt * 16 + l15][ks * 32 + q4 * 8];

#pragma unroll
    for (int ot = 0; ot < 6; ++ot) {
        int o0 = wave * 96 + ot * 16;                 // 16-row tile is purely Q, K, or V
        short8 af[4];                                 // A[m=o][k=c], m=l15 (bf16 weights)
#pragma unroll
        for (int ks = 0; ks < 4; ++ks)
            af[ks] = ldg8(wq + (size_t)(o0 + l15) * 128 + ks * 32 + q4 * 8);
        float bias[4];
#pragma unroll
        for (int r = 0; r < 4; ++r) bias[r] = qkv_b[o0 + q4 * 4 + r];
        float qs = (o0 < 128) ? QSCALE : 1.0f;

#pragma unroll
        for (int nt = 0; nt < 4; ++nt) {
            f32x4 acc = {0.f, 0.f, 0.f, 0.f};
#pragma unroll
            for (int ks = 0; ks < 4; ++ks)
                acc = MFMA_BF16(af[ks], bfrag[nt][ks], acc);
            // D[row = o0+q4*4+r][col = n0+nt*16+l15]
            int n = n0 + nt * 16 + l15;
            if (o0 < 256) {           // Q or K: [n][c] layout, 4 consecutive c -> 8B store
                unsigned short* dst = (o0 < 128) ? q_ws : k_ws;
                int oo = (o0 < 128) ? o0 : (o0 - 128);
                unsigned int lo = (unsigned int)f2bf((acc[0] + bias[0]) * qs) |
                                  ((unsigned int)f2bf((acc[1] + bias[1]) * qs) << 16);
                unsigned int hi = (unsigned int)f2bf((acc[2] + bias[2]) * qs) |
                                  ((unsigned int)f2bf((acc[3] + bias[3]) * qs) << 16);
                uint2 pk; pk.x = lo; pk.y = hi;
                *(uint2*)&dst[((size_t)(b * 4096 + n) << 7) + oo + q4 * 4] = pk;
            } else {                  // V: stage to LDS [c][n_local]
#pragma unroll
                for (int r = 0; r < 4; ++r) {
                    int c = o0 - 256 + q4 * 4 + r;
                    v_stage[c][nt * 16 + l15] = f2bf(acc[r] + bias[r]);
                }
            }
        }
    }
    __syncthreads();
    // packed V store: thread t copies half-row (32 shorts) of v_stage row c=t>>1
    {
        int c = tid >> 1, h = tid & 1;
        uint4* gdst = (uint4*)(v_ws + ((size_t)(b * 128 + c) << 12) + n0 + h * 32);
        const unsigned short* lsrc = &v_stage[c][h * 32];
#pragma unroll
        for (int k = 0; k < 4; ++k) gdst[k] = *(const uint4*)(lsrc + k * 8);
    }
}

// ---------------- Kernel 3: flash attention partial (split-KV) ----------------
// block = (b, i-tile, chunk); chunk covers 1024 j (16 iters of 64).
// K and V share one union LDS buffer (K [64][136] then V [128][72]) -> ~28 KB/block.
// Writes normalized bf16 partial O[n][c] + per-row m' = m + log2(l).
__global__ __launch_bounds__(256, 4) void k_attn_part(const unsigned short* __restrict__ q_ws,
                                                      const unsigned short* __restrict__ k_ws,
                                                      const unsigned short* __restrict__ v_ws,
                                                      unsigned short* __restrict__ o_part,
                                                      float* __restrict__ ml) {
    __shared__ unsigned short KV[9216];          // union: K 64*136=8704, V 128*72=9216
    __shared__ unsigned short P_lds[4][16][72];  // per wave [i][j]

    const int tid   = threadIdx.x;
    const int chunk = blockIdx.x & 3;
    const int tile  = (blockIdx.x >> 2) & 63;
    const int b     = blockIdx.x >> 8;
    const int i0    = tile << 6;
    const int lane  = tid & 63, wave = tid >> 6;
    const int l15   = lane & 15, q4 = lane >> 4;

    const short8 ones = {(short)0x3F80, (short)0x3F80, (short)0x3F80, (short)0x3F80,
                         (short)0x3F80, (short)0x3F80, (short)0x3F80, (short)0x3F80};

    short8 qf[4];                                // A[m=i][k=c], m=l15 (pre-scaled)
    {
        const unsigned short* qp =
            q_ws + ((size_t)(b * 4096 + i0 + wave * 16 + l15) << 7) + q4 * 8;
#pragma unroll
        for (int ks = 0; ks < 4; ++ks) qf[ks] = ldg8(qp + ks * 32);
    }

    float mrow[4];
    f32x4 lrow = {0.f, 0.f, 0.f, 0.f};
#pragma unroll
    for (int r = 0; r < 4; ++r) mrow[r] = -1e30f;
    f32x4 acc_o[8];                              // O[i=q4*4+r][c = ct*16+l15]
#pragma unroll
    for (int ct = 0; ct < 8; ++ct) acc_o[ct] = (f32x4){0.f, 0.f, 0.f, 0.f};

    const unsigned short* kbase = k_ws + ((size_t)b << 19);
    const unsigned short* vbase = v_ws + ((size_t)b << 19);

    for (int it = 0; it < 16; ++it) {
        int j0 = (chunk << 10) + (it << 6);
        __syncthreads();                          // prev iter's V reads done (buffer free)
        {   // stage K tile [64 j][136-pitch c]
            int r = tid >> 2, q = tid & 3;
            const uint4* src = (const uint4*)(kbase + ((size_t)(j0 + r) << 7) + q * 32);
            uint4* dst = (uint4*)&KV[r * 136 + q * 32];
            dst[0] = src[0]; dst[1] = src[1]; dst[2] = src[2]; dst[3] = src[3];
        }
        __syncthreads();                          // K visible

        // S = Q K^T (Q pre-scaled): D row = i (q4*4+r), col = j (l15)
        f32x4 s[4];
#pragma unroll
        for (int jt = 0; jt < 4; ++jt) {
            f32x4 a = {0.f, 0.f, 0.f, 0.f};
#pragma unroll
            for (int ks = 0; ks < 4; ++ks) {
                short8 kf = *(const short8*)&KV[(jt * 16 + l15) * 136 + ks * 32 + q4 * 8];
                a = MFMA_BF16(qf[ks], kf, a);
            }
            s[jt] = a;
        }

        // online softmax (base 2); row state in (quad,reg) space
        float al[4];
#pragma unroll
        for (int r = 0; r < 4; ++r) {
            float rm = fmaxf(fmaxf(s[0][r], s[1][r]), fmaxf(s[2][r], s[3][r]));
            rm = rowmax16(rm);
            float mn = fmaxf(mrow[r], rm);
            al[r] = EXP2(mrow[r] - mn);
            mrow[r] = mn;
        }
#pragma unroll
        for (int jt = 0; jt < 4; ++jt)
#pragma unroll
            for (int r = 0; r < 4; ++r)
                P_lds[wave][q4 * 4 + r][jt * 16 + l15] = f2bf(EXP2(s[jt][r] - mrow[r]));

        __syncthreads();                          // all K reads done -> buffer free for V
        {   // stage V tile [128 c][72-pitch j]
            int c = tid >> 1, h = tid & 1;
            const uint4* src = (const uint4*)(vbase + ((size_t)c << 12) + j0 + h * 32);
            uint4* dst = (uint4*)&KV[c * 72 + h * 32];
            dst[0] = src[0]; dst[1] = src[1]; dst[2] = src[2]; dst[3] = src[3];
        }

        // P fragments (A[m=i][k=j]) — own wave's P_lds, no barrier needed
        short8 pf0 = *(const short8*)&P_lds[wave][l15][q4 * 8];
        short8 pf1 = *(const short8*)&P_lds[wave][l15][32 + q4 * 8];

        // l = l*alpha + P.1  (ones-MFMA: every col holds the row sum)
        f32x4 lv;
#pragma unroll
        for (int r = 0; r < 4; ++r) lv[r] = lrow[r] * al[r];
        lv = MFMA_BF16(pf1, ones, MFMA_BF16(pf0, ones, lv));
        lrow = lv;

        // rescale O rows by alpha (register-local) while V staging completes
#pragma unroll
        for (int ct = 0; ct < 8; ++ct)
#pragma unroll
            for (int r = 0; r < 4; ++r) acc_o[ct][r] *= al[r];

        __syncthreads();                          // V visible

        // O += P V^T : B[k=j][n=c] read from V view [c][j]
#pragma unroll
        for (int ct = 0; ct < 8; ++ct) {
            short8 vf = *(const short8*)&KV[(ct * 16 + l15) * 72 + q4 * 8];
            acc_o[ct] = MFMA_BF16(pf0, vf, acc_o[ct]);
        }
#pragma unroll
        for (int ct = 0; ct < 8; ++ct) {
            short8 vf = *(const short8*)&KV[(ct * 16 + l15) * 72 + 32 + q4 * 8];
            acc_o[ct] = MFMA_BF16(pf1, vf, acc_o[ct]);
        }
    }

    // write normalized bf16 partial + m' = m + log2(l)
    size_t pbase = (size_t)((b * 64 + tile) * 4 + chunk) * 8192;
    float rl[4];
#pragma unroll
    for (int r = 0; r < 4; ++r) rl[r] = 1.0f / lrow[r];
#pragma unroll
    for (int ct = 0; ct < 8; ++ct)
#pragma unroll
        for (int r = 0; r < 4; ++r)
            o_part[pbase + (size_t)(wave * 16 + q4 * 4 + r) * 128 + ct * 16 + l15] =
                f2bf(acc_o[ct][r] * rl[r]);
    if (l15 == 0) {
        int mb = ((b * 64 + tile) * 4 + chunk) * 64 + wave * 16 + q4 * 4;
#pragma unroll
        for (int r = 0; r < 4; ++r) ml[mb + r] = mrow[r] + __log2f(lrow[r]);
    }
}

// ---------------- Kernel 4: merge partials + proj GEMM + bias + residual ----------
__global__ __launch_bounds__(256) void k_merge_proj(const unsigned short* __restrict__ o_part,
                                                    const float* __restrict__ ml,
                                                    const float* __restrict__ x,
                                                    const unsigned short* __restrict__ wp,
                                                    const float* __restrict__ proj_b,
                                                    float* __restrict__ out) {
    __shared__ unsigned short O_lds[64][136];
    __shared__ float wgt[64][4];
    const int tid  = threadIdx.x;
    const int b    = blockIdx.x >> 6;
    const int tile = blockIdx.x & 63;
    const int i0   = tile << 6;
    const int lane = tid & 63, wave = tid >> 6;
    const int l15  = lane & 15, q4 = lane >> 4;
    const int tb   = (b * 64 + tile) * 4;

    if (tid < 64) {
        float m0 = ml[(tb + 0) * 64 + tid], m1 = ml[(tb + 1) * 64 + tid];
        float m2 = ml[(tb + 2) * 64 + tid], m3 = ml[(tb + 3) * 64 + tid];
        float M = fmaxf(fmaxf(m0, m1), fmaxf(m2, m3));
        float w0 = EXP2(m0 - M), w1 = EXP2(m1 - M), w2 = EXP2(m2 - M), w3 = EXP2(m3 - M);
        float rW = 1.0f / (w0 + w1 + w2 + w3);
        wgt[tid][0] = w0 * rW; wgt[tid][1] = w1 * rW;
        wgt[tid][2] = w2 * rW; wgt[tid][3] = w3 * rW;
    }
    __syncthreads();

    {   // weighted merge: thread t -> row n=t>>2, 32-c quarter q=t&3
        int n = tid >> 2, q = tid & 3;
        float w[4];
#pragma unroll
        for (int ch = 0; ch < 4; ++ch) w[ch] = wgt[n][ch];
#pragma unroll
        for (int g = 0; g < 4; ++g) {             // 8 c per group
            float acc[8];
#pragma unroll
            for (int e = 0; e < 8; ++e) acc[e] = 0.f;
#pragma unroll
            for (int ch = 0; ch < 4; ++ch) {
                const unsigned short* p =
                    o_part + (size_t)(tb + ch) * 8192 + (size_t)n * 128 + q * 32 + g * 8;
                uint4 v = *(const uint4*)p;
                float wc = w[ch];
                acc[0] += wc * bf2f(v.x & 0xFFFF); acc[1] += wc * bf2f(v.x >> 16);
                acc[2] += wc * bf2f(v.y & 0xFFFF); acc[3] += wc * bf2f(v.y >> 16);
                acc[4] += wc * bf2f(v.z & 0xFFFF); acc[5] += wc * bf2f(v.z >> 16);
                acc[6] += wc * bf2f(v.w & 0xFFFF); acc[7] += wc * bf2f(v.w >> 16);
            }
            uint4 pk;
            pk.x = (unsigned int)f2bf(acc[0]) | ((unsigned int)f2bf(acc[1]) << 16);
            pk.y = (unsigned int)f2bf(acc[2]) | ((unsigned int)f2bf(acc[3]) << 16);
            pk.z = (unsigned int)f2bf(acc[4]) | ((unsigned int)f2bf(acc[5]) << 16);
            pk.w = (unsigned int)f2bf(acc[6]) | ((unsigned int)f2bf(acc[7]) << 16);
            *(uint4*)&O_lds[n][q * 32 + g * 8] = pk;
        }
    }
    __syncthreads();

    // proj GEMM: out[o][n] = sum_c proj_w[o][c] * O[n][c] + proj_b + x
    short8 bfrag[4][4];
#pragma unroll
    for (int nt = 0; nt < 4; ++nt)
#pragma unroll
        for (int ks = 0; ks < 4; ++ks)
            bfrag[nt][ks] = *(const short8*)&O_lds[nt * 16 + l15][ks * 32 + q4 * 8];

#pragma unroll
    for (int ot = 0; ot < 2; ++ot) {
        int o0 = wave * 32 + ot * 16;
        short8 af[4];
#pragma unroll
        for (int ks = 0; ks < 4; ++ks)
            af[ks] = ldg8(wp + (size_t)(o0 + l15) * 128 + ks * 32 + q4 * 8);
        float pb[4];
#pragma unroll
        for (int r = 0; r < 4; ++r) pb[r] = proj_b[o0 + q4 * 4 + r];

#pragma unroll
        for (int nt = 0; nt < 4; ++nt) {
            f32x4 acc = {0.f, 0.f, 0.f, 0.f};
#pragma unroll
            for (int ks = 0; ks < 4; ++ks)
                acc = MFMA_BF16(af[ks], bfrag[nt][ks], acc);
#pragma unroll
            for (int r = 0; r < 4; ++r) {
                size_t idx = ((size_t)(b * 128 + o0 + q4 * 4 + r) << 12) + i0 + nt * 16 + l15;
                out[idx] = x[idx] + acc[r] + pb[r];
            }
        }
    }
}

// ---------------- launch ----------------
extern "C" void kernel_launch(void* const* d_in, const int* in_sizes, int n_in,
                              void* d_out, int out_size, void* d_ws, size_t ws_size,
                              hipStream_t stream) {
    const float* x      = (const float*)d_in[0];
    const float* gn_w   = (const float*)d_in[1];
    const float* gn_b   = (const float*)d_in[2];
    const float* qkv_w  = (const float*)d_in[3];
    const float* qkv_b  = (const float*)d_in[4];
    const float* proj_w = (const float*)d_in[5];
    const float* proj_b = (const float*)d_in[6];
    float* out = (float*)d_out;

    char* ws = (char*)d_ws;
    float* stats          = (float*)ws;                              // 512 B
    unsigned short* wq    = (unsigned short*)(ws + 4096);            // 96 KB
    unsigned short* wp    = (unsigned short*)(ws + 4096 + 98304);    // 32 KB
    unsigned short* q_ws  = (unsigned short*)(ws + ((size_t)1  << 20));  // 8 MB
    unsigned short* k_ws  = (unsigned short*)(ws + ((size_t)9  << 20));  // 8 MB
    unsigned short* v_ws  = (unsigned short*)(ws + ((size_t)17 << 20));  // 8 MB
    unsigned short* o_part= (unsigned short*)(ws + ((size_t)25 << 20));  // 32 MB
    float* ml             = (float*)(ws + ((size_t)57 << 20));           // 512 KB

    k_wconv<<<64, 256, 0, stream>>>(qkv_w, proj_w, wq, wp);
    k_stats<<<64, 256, 0, stream>>>(x, stats);
    k_qkv<<<512, 256, 0, stream>>>(x, stats, gn_w, gn_b, wq, qkv_b, q_ws, k_ws, v_ws);
    k_attn_part<<<2048, 256, 0, stream>>>(q_ws, k_ws, v_ws, o_part, ml);
    k_merge_proj<<<512, 256, 0, stream>>>(o_part, ml, x, wp, proj_b, out);
}